// Round 9
// baseline (69.561 us; speedup 1.0000x reference)
//
#include <hip/hip_runtime.h>
#include <math.h>

#define BB 64
#define KMAX 512
#define DD 256
#define CC 1000
#define NBLK (BB * KMAX / 4)     // 8192 blocks, 4 rows (waves) each
#define BPB (KMAX / 4)           // 128 blocks per b

__device__ __forceinline__ float wave_reduce_sum(float v) {
    #pragma unroll
    for (int off = 32; off > 0; off >>= 1) v += __shfl_xor(v, off, 64);
    return v;
}

// Front-init: zero per-b accumulators (3x64 f32), counters (64 u32), out[0].
// 1 wave; runs before dos_main in stream order (inter-dispatch flush makes
// plain stores visible -- same mechanism as R7's out-zeroing, which passed).
__global__ void dos_init(float* __restrict__ accS, float* __restrict__ accE,
                         float* __restrict__ accEC, unsigned* __restrict__ cnt,
                         float* __restrict__ out) {
    const int t = threadIdx.x;                      // 64 threads
    accS[t] = 0.f; accE[t] = 0.f; accEC[t] = 0.f; cnt[t] = 0u;
    if (t == 0) out[0] = 0.f;
}

// Single streaming kernel (R7's proven per-row core):
//   s  = -w[b,k] * ||deep[b] - n[b,k]||            (D = 256 -> 1 float4/lane)
//   ce = log(sum_c exp(cls[b,k,c])) - cls[b,k,target[b]]
// No max-subtraction: cls ~ N(0,1), s in [-23,0] -> direct sum-exp safe in f32
// (absmax == 0.0, rounds 3-8). Dead waves skip all heavy loads.
// Tail is fused via per-b completion counters -- NO fences, NO single hot
// counter (R3's lesson):
//   thread 0: 3 fire-and-forget atomicAdds into accS/E/EC[b]
//             s_waitcnt vmcnt(0)            (adds are at coherence point)
//             relaxed fetch_add(cnt[b]); the 128th block of b becomes the
//             finisher: re-reads accs via returning RMWs (coherence-point
//             reads, no cache staleness), one atomicAdd into out[0].
__global__ void __launch_bounds__(256)
dos_main(const float* __restrict__ deep, const float* __restrict__ n,
         const float* __restrict__ w, const float* __restrict__ cls,
         const int* __restrict__ target, const int* __restrict__ lengths,
         float* __restrict__ accS, float* __restrict__ accE,
         float* __restrict__ accEC, unsigned* __restrict__ cnt,
         float* __restrict__ out) {
    const int wid  = threadIdx.x >> 6;
    const int lane = threadIdx.x & 63;
    const int row  = blockIdx.x * 4 + wid;          // b*KMAX + k
    const int b    = row >> 9;                      // KMAX = 512
    const int k    = row & (KMAX - 1);
    const int len  = lengths[b];
    const int kblk = (blockIdx.x * 4) & (KMAX - 1); // block's first k

    float sv = 0.f, ev = 0.f, ecv = 0.f;            // lane-0-meaningful
    if (k < len) {                                  // wave-uniform liveness
        // ---- issue all loads up front ----
        const float4 dv = ((const float4*)(deep + (size_t)b * DD))[lane];
        const float4 nv = ((const float4*)(n + (size_t)row * DD))[lane];
        const float* __restrict__ x = cls + (size_t)row * CC;
        const float4 v0 = ((const float4*)x)[lane];
        const float4 v1 = ((const float4*)x)[lane + 64];
        const float4 v2 = ((const float4*)x)[lane + 128];
        float4 v3 = make_float4(-1e30f, -1e30f, -1e30f, -1e30f);
        if (lane < 58) v3 = ((const float4*)x)[lane + 192];  // 250 float4 = C

        // ---- dist ----
        const float dx = dv.x - nv.x, dy = dv.y - nv.y;
        const float dz = dv.z - nv.z, dw = dv.w - nv.w;
        float acc = dx*dx + dy*dy + dz*dz + dw*dw;
        acc = wave_reduce_sum(acc);

        // ---- CE denom: direct sum-exp (-1e30 fill underflows to exactly 0) ----
        float e = __expf(v0.x) + __expf(v0.y) + __expf(v0.z) + __expf(v0.w)
                + __expf(v1.x) + __expf(v1.y) + __expf(v1.z) + __expf(v1.w)
                + __expf(v2.x) + __expf(v2.y) + __expf(v2.z) + __expf(v2.w)
                + __expf(v3.x) + __expf(v3.y) + __expf(v3.z) + __expf(v3.w);
        e = wave_reduce_sum(e);

        if (lane == 0) {
            sv  = -w[row] * sqrtf(acc);             // s[b,k]
            ev  = __expf(sv);                       // softmax numerator over k
            ecv = ev * (__logf(e) - x[target[b]]);  // exp(s) * ce
        }
    }

    __shared__ float red[4][3];
    if (lane == 0) { red[wid][0] = sv; red[wid][1] = ev; red[wid][2] = ecv; }
    __syncthreads();

    if (threadIdx.x == 0) {
        if (kblk < len) {                           // live block: contribute
            const float S  = red[0][0] + red[1][0] + red[2][0] + red[3][0];
            const float E  = red[0][1] + red[1][1] + red[2][1] + red[3][1];
            const float EC = red[0][2] + red[1][2] + red[2][2] + red[3][2];
            atomicAdd(&accS[b],  S);                // fire-and-forget, agent scope
            atomicAdd(&accE[b],  E);
            atomicAdd(&accEC[b], EC);
        }
        // Manual release: our 3 adds are complete (at coherence point) before
        // the counter increment below is issued. No cache-flush instructions.
        asm volatile("s_waitcnt vmcnt(0)" ::: "memory");
        const unsigned old = __hip_atomic_fetch_add(&cnt[b], 1u, __ATOMIC_RELAXED,
                                                    __HIP_MEMORY_SCOPE_AGENT);
        if (old == BPB - 1) {                       // finisher for this b
            const float Sb  = atomicAdd(&accS[b],  0.0f);  // RMW read: latest
            const float Eb  = atomicAdd(&accE[b],  0.0f);  // > 0 (len >= 1)
            const float ECb = atomicAdd(&accEC[b], 0.0f);
            atomicAdd(out, Sb + ECb / Eb);
        }
    }
}

extern "C" void kernel_launch(void* const* d_in, const int* in_sizes, int n_in,
                              void* d_out, int out_size, void* d_ws, size_t ws_size,
                              hipStream_t stream) {
    const float* deep    = (const float*)d_in[0];   // [B, D]
    const float* n       = (const float*)d_in[1];   // [B, KMAX, D]
    const float* w       = (const float*)d_in[2];   // [B, KMAX]
    const float* cls     = (const float*)d_in[3];   // [B, KMAX, C]
    const int*   target  = (const int*)d_in[4];     // [B]
    const int*   lengths = (const int*)d_in[5];     // [B]
    float*       out     = (float*)d_out;

    float*    ws    = (float*)d_ws;
    float*    accS  = ws;                           // [BB]
    float*    accE  = ws + BB;                      // [BB]
    float*    accEC = ws + 2 * BB;                  // [BB]
    unsigned* cnt   = (unsigned*)(ws + 3 * BB);     // [BB]

    dos_init<<<1, 64, 0, stream>>>(accS, accE, accEC, cnt, out);
    dos_main<<<NBLK, 256, 0, stream>>>(deep, n, w, cls, target, lengths,
                                       accS, accE, accEC, cnt, out);
}

// Round 10
// 24.301 us; speedup vs baseline: 2.8625x; 2.8625x over previous
//
#include <hip/hip_runtime.h>
#include <math.h>

#define BB 64
#define KMAX 512
#define DD 256
#define CC 1000
#define NLBLK (BB * KMAX / 4)    // 8192 logical blocks, 4 rows (waves) each
#define NPBLK 2048               // physical blocks (persistent, 4 iters each)
#define ITERS (NLBLK / NPBLK)    // 4
#define PPB (NLBLK / BB)         // 128 partials per b

__device__ __forceinline__ float wave_reduce_sum(float v) {
    #pragma unroll
    for (int off = 32; off > 0; off >>= 1) v += __shfl_xor(v, off, 64);
    return v;
}

// K1 (persistent): 2048 blocks x 4 grid-stride iterations over 8192 logical
// blocks; one 64-lane wave per (b,k) row, 4 rows per logical block.
//   s  = -w[b,k] * ||deep[b] - n[b,k]||            (D = 256 -> 1 float4/lane)
//   ce = log(sum_c exp(cls[b,k,c])) - cls[b,k,target[b]]
// No max-subtraction: cls ~ N(0,1), s in [-23,0] -> direct sum-exp safe in f32
// (absmax == 0.0, rounds 3-9). Dead waves skip all heavy loads; dead logical
// blocks cost one lengths read + a 12 B zero partial. Stride-2048 mapping
// interleaves live/dead logical blocks across CUs (lengths skew balance).
// Each logical block emits ONE non-atomic partial triple; no atomics, no
// fences, no counters (R3/R6/R9 lessons). Block 0 zeroes out[0] for K2.
__global__ void __launch_bounds__(256)
dos_row_kernel(const float* __restrict__ deep, const float* __restrict__ n,
               const float* __restrict__ w, const float* __restrict__ cls,
               const int* __restrict__ target, const int* __restrict__ lengths,
               float* __restrict__ part_s, float* __restrict__ part_e,
               float* __restrict__ part_ec, float* __restrict__ out) {
    const int wid  = threadIdx.x >> 6;
    const int lane = threadIdx.x & 63;

    if (blockIdx.x == 0 && threadIdx.x == 0) out[0] = 0.f;

    __shared__ float red[4][3];

    for (int it = 0; it < ITERS; ++it) {
        const int lb  = blockIdx.x + it * NPBLK;    // logical block id
        const int row = lb * 4 + wid;               // b*KMAX + k
        const int b   = row >> 9;                   // KMAX = 512
        const int k   = row & (KMAX - 1);
        const int len = lengths[b];

        if (((lb * 4) & (KMAX - 1)) >= len) {       // fully-dead logical block
            if (threadIdx.x == 0) {
                part_s[lb] = 0.f; part_e[lb] = 0.f; part_ec[lb] = 0.f;
            }
            continue;                               // block-uniform
        }

        float sv = 0.f, ev = 0.f, ecv = 0.f;        // lane-0-meaningful
        if (k < len) {                              // wave-uniform liveness
            // ---- issue all loads up front ----
            const float4 dv = ((const float4*)(deep + (size_t)b * DD))[lane];
            const float4 nv = ((const float4*)(n + (size_t)row * DD))[lane];
            const float* __restrict__ x = cls + (size_t)row * CC;
            const float4 v0 = ((const float4*)x)[lane];
            const float4 v1 = ((const float4*)x)[lane + 64];
            const float4 v2 = ((const float4*)x)[lane + 128];
            float4 v3 = make_float4(-1e30f, -1e30f, -1e30f, -1e30f);
            if (lane < 58) v3 = ((const float4*)x)[lane + 192];  // 250 float4

            // ---- dist ----
            const float dx = dv.x - nv.x, dy = dv.y - nv.y;
            const float dz = dv.z - nv.z, dw = dv.w - nv.w;
            float acc = dx*dx + dy*dy + dz*dz + dw*dw;
            acc = wave_reduce_sum(acc);

            // ---- CE denom: direct sum-exp (-1e30 fill underflows to 0) ----
            float e = __expf(v0.x) + __expf(v0.y) + __expf(v0.z) + __expf(v0.w)
                    + __expf(v1.x) + __expf(v1.y) + __expf(v1.z) + __expf(v1.w)
                    + __expf(v2.x) + __expf(v2.y) + __expf(v2.z) + __expf(v2.w)
                    + __expf(v3.x) + __expf(v3.y) + __expf(v3.z) + __expf(v3.w);
            e = wave_reduce_sum(e);

            if (lane == 0) {
                sv  = -w[row] * sqrtf(acc);         // s[b,k]
                ev  = __expf(sv);                   // softmax numerator over k
                ecv = ev * (__logf(e) - x[target[b]]);
            }
        }

        __syncthreads();                            // reuse red[] across iters
        if (lane == 0) { red[wid][0] = sv; red[wid][1] = ev; red[wid][2] = ecv; }
        __syncthreads();
        if (threadIdx.x == 0) {
            part_s[lb]  = red[0][0] + red[1][0] + red[2][0] + red[3][0];
            part_e[lb]  = red[0][1] + red[1][1] + red[2][1] + red[3][1];
            part_ec[lb] = red[0][2] + red[1][2] + red[2][2] + red[3][2];
        }
    }
}

// K2: 64 blocks (one per b) x 128 threads; sum the 128 partial triples of b,
// then one atomicAdd(out, sumS + sumEC/sumE). out zeroed by K1.
__global__ void __launch_bounds__(128)
dos_final_kernel(const float* __restrict__ part_s, const float* __restrict__ part_e,
                 const float* __restrict__ part_ec, float* __restrict__ out) {
    const int b = blockIdx.x;
    const int t = threadIdx.x;                      // 128 threads = PPB
    float ss = part_s[b * PPB + t];
    float se = part_e[b * PPB + t];
    float sc = part_ec[b * PPB + t];
    ss = wave_reduce_sum(ss);
    se = wave_reduce_sum(se);
    sc = wave_reduce_sum(sc);

    __shared__ float r[2][3];
    if ((t & 63) == 0) { r[t >> 6][0] = ss; r[t >> 6][1] = se; r[t >> 6][2] = sc; }
    __syncthreads();
    if (t == 0) {
        const float S  = r[0][0] + r[1][0];
        const float E  = r[0][1] + r[1][1];        // > 0 (len >= 1)
        const float EC = r[0][2] + r[1][2];
        atomicAdd(out, S + EC / E);
    }
}

extern "C" void kernel_launch(void* const* d_in, const int* in_sizes, int n_in,
                              void* d_out, int out_size, void* d_ws, size_t ws_size,
                              hipStream_t stream) {
    const float* deep    = (const float*)d_in[0];   // [B, D]
    const float* n       = (const float*)d_in[1];   // [B, KMAX, D]
    const float* w       = (const float*)d_in[2];   // [B, KMAX]
    const float* cls     = (const float*)d_in[3];   // [B, KMAX, C]
    const int*   target  = (const int*)d_in[4];     // [B]
    const int*   lengths = (const int*)d_in[5];     // [B]
    float*       out     = (float*)d_out;

    float* ws      = (float*)d_ws;
    float* part_s  = ws;                            // [NLBLK]
    float* part_e  = ws + NLBLK;                    // [NLBLK]
    float* part_ec = ws + 2 * NLBLK;                // [NLBLK]

    dos_row_kernel<<<NPBLK, 256, 0, stream>>>(deep, n, w, cls, target, lengths,
                                              part_s, part_e, part_ec, out);
    dos_final_kernel<<<BB, PPB, 0, stream>>>(part_s, part_e, part_ec, out);
}

// Round 11
// 23.941 us; speedup vs baseline: 2.9054x; 1.0150x over previous
//
#include <hip/hip_runtime.h>
#include <math.h>

#define BB 64
#define KMAX 512
#define DD 256
#define CC 1000
#define NBLK1 (BB * KMAX / 4)   // 8192 blocks, 4 rows (waves) each
#define PPB 128                 // partial slots per b (= KMAX/4); only ceil(len/4) live

__device__ __forceinline__ float wave_reduce_sum(float v) {
    #pragma unroll
    for (int off = 32; off > 0; off >>= 1) v += __shfl_xor(v, off, 64);
    return v;
}

// K1: one 64-lane wave per (b,k) row; 4 rows (same b) per block. (R7 core.)
//   s  = -w[b,k] * ||deep[b] - n[b,k]||             (D = 256 -> 1 float4/lane)
//   ce = log(sum_c exp(cls[b,k,c])) - cls[b,k,target[b]]
// No max-subtraction: cls ~ N(0,1), s in [-23,0] -> direct sum-exp safe in f32
// (absmax == 0.0, rounds 3-10).
// Dead waves skip all heavy loads. Fully-dead blocks exit on the lengths read
// alone -- they write NOTHING (K2 only reads the live ceil(len/4) partials).
// Live blocks write ONE non-atomic partial triple. No atomics, no fences, no
// counters, no out-zeroing (R3/R6/R9 lessons; K2 writes out directly).
__global__ void __launch_bounds__(256)
dos_row_kernel(const float* __restrict__ deep, const float* __restrict__ n,
               const float* __restrict__ w, const float* __restrict__ cls,
               const int* __restrict__ target, const int* __restrict__ lengths,
               float* __restrict__ part_s, float* __restrict__ part_e,
               float* __restrict__ part_ec) {
    const int wid  = threadIdx.x >> 6;
    const int lane = threadIdx.x & 63;
    const int row  = blockIdx.x * 4 + wid;          // b*KMAX + k
    const int b    = row >> 9;                      // KMAX = 512
    const int k    = row & (KMAX - 1);
    const int len  = lengths[b];

    if (((blockIdx.x * 4) & (KMAX - 1)) >= len)     // fully-dead block:
        return;                                     // zero stores, zero LDS work

    float sv = 0.f, ev = 0.f, ecv = 0.f;            // lane-0-meaningful
    if (k < len) {                                  // wave-uniform liveness
        // ---- issue all loads up front ----
        const float4 dv = ((const float4*)(deep + (size_t)b * DD))[lane];
        const float4 nv = ((const float4*)(n + (size_t)row * DD))[lane];
        const float* __restrict__ x = cls + (size_t)row * CC;
        const float4 v0 = ((const float4*)x)[lane];
        const float4 v1 = ((const float4*)x)[lane + 64];
        const float4 v2 = ((const float4*)x)[lane + 128];
        float4 v3 = make_float4(-1e30f, -1e30f, -1e30f, -1e30f);
        if (lane < 58) v3 = ((const float4*)x)[lane + 192];  // 250 float4 = C

        // ---- dist ----
        const float dx = dv.x - nv.x, dy = dv.y - nv.y;
        const float dz = dv.z - nv.z, dw = dv.w - nv.w;
        float acc = dx*dx + dy*dy + dz*dz + dw*dw;
        acc = wave_reduce_sum(acc);

        // ---- CE denom: direct sum-exp (-1e30 fill underflows to exactly 0) ----
        float e = __expf(v0.x) + __expf(v0.y) + __expf(v0.z) + __expf(v0.w)
                + __expf(v1.x) + __expf(v1.y) + __expf(v1.z) + __expf(v1.w)
                + __expf(v2.x) + __expf(v2.y) + __expf(v2.z) + __expf(v2.w)
                + __expf(v3.x) + __expf(v3.y) + __expf(v3.z) + __expf(v3.w);
        e = wave_reduce_sum(e);

        if (lane == 0) {
            sv  = -w[row] * sqrtf(acc);             // s[b,k]
            ev  = __expf(sv);                       // softmax numerator over k
            ecv = ev * (__logf(e) - x[target[b]]);  // exp(s) * ce
        }
    }

    __shared__ float red[4][3];
    if (lane == 0) { red[wid][0] = sv; red[wid][1] = ev; red[wid][2] = ecv; }
    __syncthreads();
    if (threadIdx.x == 0) {
        part_s[blockIdx.x]  = red[0][0] + red[1][0] + red[2][0] + red[3][0];
        part_e[blockIdx.x]  = red[0][1] + red[1][1] + red[2][1] + red[3][1];
        part_ec[blockIdx.x] = red[0][2] + red[1][2] + red[2][2] + red[3][2];
    }
}

// K2: ONE block, 1024 threads, atomic-free. 16 threads per b gather that b's
// live partials (j < ceil(len/4), <=8 each), width-16 shuffle reduce, per-b
// values to LDS, wave 0 sums the 64 values, thread 0 writes out[0] directly.
__global__ void __launch_bounds__(1024)
dos_final_kernel(const float* __restrict__ part_s, const float* __restrict__ part_e,
                 const float* __restrict__ part_ec, const int* __restrict__ lengths,
                 float* __restrict__ out) {
    const int t      = threadIdx.x;                 // 0..1023
    const int b      = t >> 4;                      // 16 threads per b
    const int lane16 = t & 15;
    const int nlive  = (lengths[b] + 3) >> 2;       // live partials of b (>=1)

    float ss = 0.f, se = 0.f, sc = 0.f;
    for (int j = lane16; j < nlive; j += 16) {      // <= 8 iterations
        const int idx = b * PPB + j;
        ss += part_s[idx]; se += part_e[idx]; sc += part_ec[idx];
    }
    #pragma unroll
    for (int off = 8; off > 0; off >>= 1) {         // reduce within 16-lane group
        ss += __shfl_xor(ss, off, 16);
        se += __shfl_xor(se, off, 16);
        sc += __shfl_xor(sc, off, 16);
    }

    __shared__ float sval[BB];
    if (lane16 == 0) sval[b] = ss + sc / se;        // se > 0 (len >= 1)
    __syncthreads();
    if (t < 64) {
        float v = sval[t];
        v = wave_reduce_sum(v);
        if (t == 0) out[0] = v;
    }
}

extern "C" void kernel_launch(void* const* d_in, const int* in_sizes, int n_in,
                              void* d_out, int out_size, void* d_ws, size_t ws_size,
                              hipStream_t stream) {
    const float* deep    = (const float*)d_in[0];   // [B, D]
    const float* n       = (const float*)d_in[1];   // [B, KMAX, D]
    const float* w       = (const float*)d_in[2];   // [B, KMAX]
    const float* cls     = (const float*)d_in[3];   // [B, KMAX, C]
    const int*   target  = (const int*)d_in[4];     // [B]
    const int*   lengths = (const int*)d_in[5];     // [B]
    float*       out     = (float*)d_out;

    float* ws      = (float*)d_ws;
    float* part_s  = ws;                            // [NBLK1]
    float* part_e  = ws + NBLK1;                    // [NBLK1]
    float* part_ec = ws + 2 * NBLK1;                // [NBLK1]

    dos_row_kernel<<<NBLK1, 256, 0, stream>>>(deep, n, w, cls, target, lengths,
                                              part_s, part_e, part_ec);
    dos_final_kernel<<<1, 1024, 0, stream>>>(part_s, part_e, part_ec, lengths, out);
}

// Round 12
// 22.195 us; speedup vs baseline: 3.1341x; 1.0787x over previous
//
#include <hip/hip_runtime.h>
#include <math.h>

#define BB 64
#define KMAX 512
#define DD 256
#define CC 1000
#define NBLK1 (BB * KMAX / 4)   // 8192 blocks, 4 rows (waves) each
#define PPB 128                 // partials per b in K2 (= NBLK1 / BB)

__device__ __forceinline__ float wave_reduce_sum(float v) {
    #pragma unroll
    for (int off = 32; off > 0; off >>= 1) v += __shfl_xor(v, off, 64);
    return v;
}

// K1: one 64-lane wave per (b,k) row; 4 rows (same b) per block.
//   s  = -w[b,k] * ||deep[b] - n[b,k]||             (D = 256 -> 1 float4/lane)
//   ce = log(sum_c exp(cls[b,k,c])) - cls[b,k,target[b]]
// No max-subtraction: cls ~ N(0,1), s in [-23,0] -> direct sum-exp safe in f32
// (validated absmax == 0.0 in rounds 3-11).
// Dead waves (k >= lengths[b]) skip all heavy loads; fully-dead blocks write a
// zero partial. Each block writes ONE non-atomic partial triple:
//   part_s[blk]  = sum_rows s,  part_e[blk] = sum_rows exp(s),
//   part_ec[blk] = sum_rows exp(s)*ce
// Block 0 thread 0 zeroes out[0] for K2's atomicAdd (stream-ordered).
// [Empirical best structure: R7 = 22.41 us. Seven structural variants
//  (fused single-kernel w/ counters, memset-init, 2/4-rows-per-wave,
//  persistent grid, storeless dead blocks, single-block K2) all regressed.]
__global__ void __launch_bounds__(256)
dos_row_kernel(const float* __restrict__ deep, const float* __restrict__ n,
               const float* __restrict__ w, const float* __restrict__ cls,
               const int* __restrict__ target, const int* __restrict__ lengths,
               float* __restrict__ part_s, float* __restrict__ part_e,
               float* __restrict__ part_ec, float* __restrict__ out) {
    const int wid  = threadIdx.x >> 6;
    const int lane = threadIdx.x & 63;
    const int row  = blockIdx.x * 4 + wid;          // b*KMAX + k
    const int b    = row >> 9;                      // KMAX = 512
    const int k    = row & (KMAX - 1);
    const int len  = lengths[b];

    if (blockIdx.x == 0 && threadIdx.x == 0) out[0] = 0.f;

    // Fully-dead block (k uniform within 4-row group up to the boundary wave):
    if ((blockIdx.x * 4 & (KMAX - 1)) >= len) {
        if (threadIdx.x == 0) {
            part_s[blockIdx.x] = 0.f; part_e[blockIdx.x] = 0.f; part_ec[blockIdx.x] = 0.f;
        }
        return;                                     // block-uniform exit
    }

    float sv = 0.f, ev = 0.f, ecv = 0.f;
    if (k < len) {                                  // wave-uniform
        // ---- issue all loads up front ----
        const float4 dv = ((const float4*)(deep + (size_t)b * DD))[lane];
        const float4 nv = ((const float4*)(n + (size_t)row * DD))[lane];
        const float* __restrict__ x = cls + (size_t)row * CC;
        const float4 v0 = ((const float4*)x)[lane];
        const float4 v1 = ((const float4*)x)[lane + 64];
        const float4 v2 = ((const float4*)x)[lane + 128];
        float4 v3 = make_float4(-1e30f, -1e30f, -1e30f, -1e30f);
        if (lane < 58) v3 = ((const float4*)x)[lane + 192];  // 250 float4 = C

        // ---- dist ----
        const float dx = dv.x - nv.x, dy = dv.y - nv.y;
        const float dz = dv.z - nv.z, dw = dv.w - nv.w;
        float acc = dx*dx + dy*dy + dz*dz + dw*dw;
        acc = wave_reduce_sum(acc);

        // ---- CE denom: direct sum-exp (-1e30 fill underflows to exactly 0) ----
        float e = __expf(v0.x) + __expf(v0.y) + __expf(v0.z) + __expf(v0.w)
                + __expf(v1.x) + __expf(v1.y) + __expf(v1.z) + __expf(v1.w)
                + __expf(v2.x) + __expf(v2.y) + __expf(v2.z) + __expf(v2.w)
                + __expf(v3.x) + __expf(v3.y) + __expf(v3.z) + __expf(v3.w);
        e = wave_reduce_sum(e);

        if (lane == 0) {
            sv  = -w[row] * sqrtf(acc);             // s[b,k]
            ev  = __expf(sv);                       // softmax numerator over k
            ecv = ev * (__logf(e) - x[target[b]]);  // exp(s) * ce
        }
    }

    __shared__ float red[4][3];
    if (lane == 0) { red[wid][0] = sv; red[wid][1] = ev; red[wid][2] = ecv; }
    __syncthreads();
    if (threadIdx.x == 0) {
        part_s[blockIdx.x]  = red[0][0] + red[1][0] + red[2][0] + red[3][0];
        part_e[blockIdx.x]  = red[0][1] + red[1][1] + red[2][1] + red[3][1];
        part_ec[blockIdx.x] = red[0][2] + red[1][2] + red[2][2] + red[3][2];
    }
}

// K2: 64 blocks (one per b) x 128 threads; sum the 128 partial triples of b,
// then one atomicAdd(out, sumS + sumEC/sumE). out zeroed by K1.
__global__ void __launch_bounds__(128)
dos_final_kernel(const float* __restrict__ part_s, const float* __restrict__ part_e,
                 const float* __restrict__ part_ec, float* __restrict__ out) {
    const int b = blockIdx.x;
    const int t = threadIdx.x;                      // 128 threads = PPB
    float ss = part_s[b * PPB + t];
    float se = part_e[b * PPB + t];
    float sc = part_ec[b * PPB + t];
    ss = wave_reduce_sum(ss);
    se = wave_reduce_sum(se);
    sc = wave_reduce_sum(sc);

    __shared__ float r[2][3];
    if ((t & 63) == 0) { r[t >> 6][0] = ss; r[t >> 6][1] = se; r[t >> 6][2] = sc; }
    __syncthreads();
    if (t == 0) {
        const float S  = r[0][0] + r[1][0];
        const float E  = r[0][1] + r[1][1];        // > 0 (len >= 1)
        const float EC = r[0][2] + r[1][2];
        atomicAdd(out, S + EC / E);
    }
}

extern "C" void kernel_launch(void* const* d_in, const int* in_sizes, int n_in,
                              void* d_out, int out_size, void* d_ws, size_t ws_size,
                              hipStream_t stream) {
    const float* deep    = (const float*)d_in[0];   // [B, D]
    const float* n       = (const float*)d_in[1];   // [B, KMAX, D]
    const float* w       = (const float*)d_in[2];   // [B, KMAX]
    const float* cls     = (const float*)d_in[3];   // [B, KMAX, C]
    const int*   target  = (const int*)d_in[4];     // [B]
    const int*   lengths = (const int*)d_in[5];     // [B]
    float*       out     = (float*)d_out;

    float* ws      = (float*)d_ws;
    float* part_s  = ws;                            // [NBLK1]
    float* part_e  = ws + NBLK1;                    // [NBLK1]
    float* part_ec = ws + 2 * NBLK1;                // [NBLK1]

    dos_row_kernel<<<NBLK1, 256, 0, stream>>>(deep, n, w, cls, target, lengths,
                                              part_s, part_e, part_ec, out);
    dos_final_kernel<<<BB, PPB, 0, stream>>>(part_s, part_e, part_ec, out);
}